// Round 7
// baseline (793.376 us; speedup 1.0000x reference)
//
#include <hip/hip_runtime.h>
#include <hip/hip_bf16.h>
#include <math.h>

#define HW   4096
#define CCH  256
#define NE   8
#define HID  512
#define NTOK 65536

typedef short s16x8 __attribute__((ext_vector_type(8)));
typedef float f32x4 __attribute__((ext_vector_type(4)));
typedef unsigned short u16x8 __attribute__((ext_vector_type(8)));
typedef unsigned short u16x4 __attribute__((ext_vector_type(4)));

// Fast exact-enough GELU: v * sigmoid(2u), u = 0.79788456*(v + 0.044715 v^3).
__device__ __forceinline__ float fast_gelu(float v) {
    float v2 = v * v;
    float s  = v * fmaf(0.10294324f, v2, 2.3022079f);
    float e  = exp2f(-s);
    return v * __builtin_amdgcn_rcpf(1.0f + e);
}

__device__ __forceinline__ float bfbits2f(unsigned short h) {
    return __uint_as_float(((unsigned)h) << 16);
}

__device__ __forceinline__ short f2bf_bits(float f) {
    __hip_bfloat16 b = __float2bfloat16(f);
    return *reinterpret_cast<short*>(&b);
}

__device__ __forceinline__ unsigned short f2bf_ubits(float f) {
    __hip_bfloat16 b = __float2bfloat16(f);
    return *reinterpret_cast<unsigned short*>(&b);
}

// Hidden-permutation for w2t (see k_expert): storage pos n within each
// 32-block for physical hidden p: n = ((p&15)>>2)*8 + ((p>>4)&1)*4 + (p&3).
__device__ __forceinline__ int hperm(int h) {
    return (h & ~31) | (((h & 15) >> 2) << 3) | (((h >> 4) & 1) << 2) | (h & 3);
}

// ---------------- K transpose+cast for BOTH weights (+ meta zero) -----------
// blocks [0,256): W1 (E,256,512)->(E,512,256) [unpermuted];
// blocks [256,512): W2 (E,512,256)->(E,256,512) with hidden-index PERMUTED
// within each 32-block (matches k_expert's packed GEMM1->GEMM2 fragment order).
__global__ __launch_bounds__(256) void k_transpose_both(
    const float* __restrict__ W1, const float* __restrict__ W2,
    __hip_bfloat16* __restrict__ w1t, __hip_bfloat16* __restrict__ w2t,
    int* __restrict__ meta)
{
    __shared__ float t[64][65];
    if (blockIdx.x == 0 && threadIdx.x < 16) meta[threadIdx.x] = 0;  // counts+cursors
    int bb = blockIdx.x;
    int isW2 = bb >= 256;
    const float* in; __hip_bfloat16* out; int R, CC;
    if (!isW2) { in = W1; out = w1t; R = 256; CC = 512; }
    else       { in = W2; out = w2t; R = 512; CC = 256; bb -= 256; }
    int tilesC = CC >> 6;
    int per = (R >> 6) * tilesC;
    int e = bb / per, tt = bb % per;
    int r0 = (tt / tilesC) << 6, c0 = (tt % tilesC) << 6;
    const float* ip = in + (size_t)e * R * CC;
    __hip_bfloat16* op = out + (size_t)e * R * CC;
    int lane = threadIdx.x & 63, g = threadIdx.x >> 6;
    for (int i = 0; i < 16; i++) {
        int r = i * 4 + g;
        t[r][lane] = ip[(size_t)(r0 + r) * CC + c0 + lane];
    }
    __syncthreads();
    for (int i = 0; i < 16; i++) {
        int r = i * 4 + g;
        int h = r0 + lane;                       // source row index (hidden for W2)
        int hp = isW2 ? hperm(h) : h;
        op[(size_t)(c0 + r) * R + hp] = __float2bfloat16(t[lane][r]);
    }
}

// ---------------- K0: router, 32-token tiles, fused reg-logits --------------
__global__ __launch_bounds__(256) void k_router(
    const float* __restrict__ x, const float* __restrict__ Wr, const float* __restrict__ br,
    __hip_bfloat16* __restrict__ tokens, int* __restrict__ pair, float2* __restrict__ wts,
    int* __restrict__ meta /* counts at [0..8) */)
{
    __shared__ float xt[CCH][33];      // 33.8 KB
    __shared__ float wrp[2304];        // Wr staged [c*8+e]; reused as plg
    __shared__ float lg[32][NE];
    __shared__ int lc[NE];
    int tid = threadIdx.x;
    int n0 = blockIdx.x * 32;
    int b = n0 >> 12, p0 = n0 & 4095;
    const float* xb = x + (size_t)b * CCH * HW + p0;
    for (int i = tid; i < CCH * NE; i += 256) wrp[i] = Wr[i];
    if (tid < NE) lc[tid] = 0;
    __syncthreads();
    int j = tid & 31, cg = tid >> 5;
    float pacc[8];
#pragma unroll
    for (int e = 0; e < 8; e++) pacc[e] = 0.f;
    for (int i = 0; i < 32; i++) {
        int c = cg + 8 * i;
        float xv = xb[(size_t)c * HW + j];
        xt[c][j] = xv;
        const float4* wp = (const float4*)(wrp + c * 8);
        float4 wa = wp[0], wb2 = wp[1];
        pacc[0] = fmaf(xv, wa.x, pacc[0]);
        pacc[1] = fmaf(xv, wa.y, pacc[1]);
        pacc[2] = fmaf(xv, wa.z, pacc[2]);
        pacc[3] = fmaf(xv, wa.w, pacc[3]);
        pacc[4] = fmaf(xv, wb2.x, pacc[4]);
        pacc[5] = fmaf(xv, wb2.y, pacc[5]);
        pacc[6] = fmaf(xv, wb2.z, pacc[6]);
        pacc[7] = fmaf(xv, wb2.w, pacc[7]);
    }
    __syncthreads();
    float* plg = wrp;
#pragma unroll
    for (int e = 0; e < 8; e++) plg[(cg * 32 + j) * 9 + e] = pacc[e];
    __syncthreads();
    {
        int jj = tid & 31, e = tid >> 5;
        float s = br[e];
#pragma unroll
        for (int g = 0; g < 8; g++) s += plg[(g * 32 + jj) * 9 + e];
        lg[jj][e] = s;
    }
    __syncthreads();
    if (tid < 32) {
        float v0 = -1e30f, v1 = -1e30f; int i0 = 0, i1 = 0;
        for (int e = 0; e < NE; e++) {
            float l = lg[tid][e];
            if (l > v0)      { v1 = v0; i1 = i0; v0 = l; i0 = e; }
            else if (l > v1) { v1 = l; i1 = e; }
        }
        float e1 = expf(v1 - v0);
        float s = 1.0f + e1;
        wts[n0 + tid] = make_float2(1.0f / s, e1 / s);
        pair[n0 + tid] = i0 | (i1 << 8);
        atomicAdd(&lc[i0], 1);
        atomicAdd(&lc[i1], 1);
    }
    __syncthreads();
    if (tid < NE && lc[tid] > 0) atomicAdd(&meta[tid], lc[tid]);
#pragma unroll
    for (int i = 0; i < 4; i++) {
        int c0 = (cg + 8 * i) * 8;
        s16x8 v;
#pragma unroll
        for (int k = 0; k < 8; k++) v[k] = f2bf_bits(xt[c0 + k][j]);
        *(s16x8*)(tokens + (size_t)(n0 + j) * CCH + c0) = v;
    }
}

// ---------------- K2: scatter tokens into per-expert lists (scan fused) -----
// meta: [0..8) counts, [8..16) cursors, [16..25) offsets, [25..34) tilestart, [34] total
// 16-token tiles (k_expert is now 1-wave/16-token).
__global__ __launch_bounds__(256) void k_scatter(
    const int* __restrict__ pair, const float2* __restrict__ wts,
    int* __restrict__ meta, int* __restrict__ assign_tok, float* __restrict__ assign_w,
    int2* __restrict__ tok_slots)
{
    __shared__ int lcount[NE];
    __shared__ int lbase[NE];
    __shared__ int soff[NE];
    int tid = threadIdx.x;
    int n = blockIdx.x * 256 + tid;
    if (tid < NE) lcount[tid] = 0;
    __syncthreads();
    int pr = pair[n];
    int e0 = pr & 0xff, e1 = (pr >> 8) & 0xff;
    int p0 = atomicAdd(&lcount[e0], 1);
    int p1 = atomicAdd(&lcount[e1], 1);
    __syncthreads();
    if (tid == 0) {
        int off = 0, toff = 0;
        for (int ee = 0; ee < NE; ee++) {
            soff[ee] = off;
            int c = meta[ee];
            if (blockIdx.x == 0) { meta[16 + ee] = off; meta[25 + ee] = toff; }
            off += c;
            toff += (c + 15) >> 4;
        }
        if (blockIdx.x == 0) { meta[24] = off; meta[33] = toff; meta[34] = toff; }
    }
    if (tid < NE) lbase[tid] = atomicAdd(&meta[8 + tid], lcount[tid]);
    __syncthreads();
    float2 w = wts[n];
    int s0 = soff[e0] + lbase[e0] + p0;
    int s1 = soff[e1] + lbase[e1] + p1;
    assign_tok[s0] = n; assign_w[s0] = w.x;
    assign_tok[s1] = n; assign_w[s1] = w.y;
    tok_slots[n] = make_int2(s0, s1);
}

// ---------------- K3: barrier-free 1-wave grouped MLP -----------------------
// R7 rewrite: 1 wave per block, 16-token tile, ZERO barriers.
// GEMM1 computed SWAPPED: mfma(A=W1^T frag, B=token frag) -> D=H[hidden][token]
// (token in lane dim, hidden in reg dim) == GEMM2's A-operand layout. GELU +
// bf16-pack in-register; the induced hidden permutation (k=q*8+j <-> p=
// (j>=4)*16+q*4+(j&3)) is baked into w2t by k_transpose_both. No Hs, no
// __syncthreads; 16 fully independent waves/CU (regs<=128 via launch_bounds).
// Weights stream from per-XCD L2 (XCD swizzle keeps them resident, R4-proven).
__global__ __launch_bounds__(64, 4) void k_expert(
    const __hip_bfloat16* __restrict__ tokens,
    const __hip_bfloat16* __restrict__ w1t,   // (E, HID, C)  = W1^T
    const __hip_bfloat16* __restrict__ w2t,   // (E, C, HID)  = W2^T, hidden-permuted
    const float* __restrict__ b1, const float* __restrict__ b2,
    const int* __restrict__ meta,
    const int* __restrict__ assign_tok, const float* __restrict__ assign_w,
    __hip_bfloat16* __restrict__ ybuf)
{
    __shared__ __align__(16) __hip_bfloat16 Af[16 * 256];   // 8 KB, frag-linear

    int total = meta[34];
    int swz = (int)blockIdx.x;
    int bid = (swz & 7) * 1025 + (swz >> 3);   // grid 8200 = 8 XCDs x 1025, bijective
    if (bid >= total) return;
    int e = 0;
    while (e < 7 && bid >= meta[25 + e + 1]) e++;
    int tile = bid - meta[25 + e];
    int cnt = meta[e];
    int r0 = tile << 4;
    int abase = meta[16 + e] + r0;
    int nrows = cnt - r0; if (nrows > 16) nrows = 16;

    int lane = threadIdx.x;            // 0..63 (1 wave)
    int quad = lane >> 4, l15 = lane & 15;

    // token row for this lane's column (pad columns reuse row 0; discarded on store)
    int tok = assign_tok[abase + (l15 < nrows ? l15 : 0)];

    // ---- stage Af frag-linear: unit u = kk*64 + quad*16 + l15 holds
    //      tokens[tok(l15)][kk*32 + quad*8 + j]   (j=0..7)
    {
        const uint4* tsrc = (const uint4*)(tokens + (size_t)tok * CCH);
        uint4* afu = (uint4*)Af;
#pragma unroll
        for (int i = 0; i < 8; i++)
            afu[i * 64 + lane] = tsrc[i * 4 + quad];
    }

    const __hip_bfloat16* w1e = w1t + (size_t)e * HID * CCH;   // [hid][chan]
    const __hip_bfloat16* w2e = w2t + (size_t)e * CCH * HID;   // [outcol][hid-perm]
    const float* b1e = b1 + e * HID;

    f32x4 oacc[16];
#pragma unroll
    for (int o = 0; o < 16; o++) oacc[o] = (f32x4){0.f, 0.f, 0.f, 0.f};

    // first W1 frags for chunk 0 (A-operand rows = hidden, k = channel)
    s16x8 wf0 = *((const s16x8*)(w1e + (size_t)(l15) * CCH) + quad);
    s16x8 wf1 = *((const s16x8*)(w1e + (size_t)(16 + l15) * CCH) + quad);

    for (int ch = 0; ch < 16; ch++) {          // 16 chunks x 32 hiddens
        const s16x8* a0 = (const s16x8*)(w1e + (size_t)(ch * 32      + l15) * CCH) + quad;
        const s16x8* a1 = (const s16x8*)(w1e + (size_t)(ch * 32 + 16 + l15) * CCH) + quad;

        // biases for this chunk (complete during GEMM1)
        float bv0[4], bv1[4];
#pragma unroll
        for (int r = 0; r < 4; r++) {
            bv0[r] = b1e[ch * 32 + quad * 4 + r];
            bv1[r] = b1e[ch * 32 + 16 + quad * 4 + r];
        }

        // ---- GEMM1 (swapped): h = W1 x tokens^T, K=256
        f32x4 h0 = (f32x4){0.f, 0.f, 0.f, 0.f};
        f32x4 h1 = (f32x4){0.f, 0.f, 0.f, 0.f};
#pragma unroll
        for (int kk = 0; kk < 8; kk++) {
            s16x8 wn0, wn1;
            if (kk < 7) { wn0 = a0[(kk + 1) * 4]; wn1 = a1[(kk + 1) * 4]; }
            s16x8 tf = ((const s16x8*)Af)[kk * 64 + lane];
            __builtin_amdgcn_s_setprio(1);
            h0 = __builtin_amdgcn_mfma_f32_16x16x32_bf16(wf0, tf, h0, 0, 0, 0);
            h1 = __builtin_amdgcn_mfma_f32_16x16x32_bf16(wf1, tf, h1, 0, 0, 0);
            __builtin_amdgcn_s_setprio(0);
            if (kk < 7) { wf0 = wn0; wf1 = wn1; }
        }
        // prefetch next chunk's first W1 frags (complete under GEMM2)
        if (ch < 15) {
            wf0 = *((const s16x8*)(w1e + (size_t)((ch + 1) * 32      + l15) * CCH) + quad);
            wf1 = *((const s16x8*)(w1e + (size_t)((ch + 1) * 32 + 16 + l15) * CCH) + quad);
        }

        // ---- bias + GELU + pack: a2[j] holds H[p][tok=l15], p = (j>=4)*16+q*4+(j&3)
        s16x8 a2;
#pragma unroll
        for (int r = 0; r < 4; r++) {
            a2[r]     = f2bf_bits(fast_gelu(h0[r] + bv0[r]));
            a2[4 + r] = f2bf_bits(fast_gelu(h1[r] + bv1[r]));
        }

        // ---- GEMM2: out += H-chunk x W2-chunk (hidden-permuted w2t), 16 outcol tiles
        const __hip_bfloat16* w2b = w2e + (size_t)l15 * HID + ch * 32;
        s16x8 cf = *((const s16x8*)w2b + quad);
#pragma unroll
        for (int o = 0; o < 16; o++) {
            s16x8 cn;
            if (o < 15) cn = *((const s16x8*)(w2b + (size_t)(o + 1) * (16 * HID)) + quad);
            __builtin_amdgcn_s_setprio(1);
            oacc[o] = __builtin_amdgcn_mfma_f32_16x16x32_bf16(a2, cf, oacc[o], 0, 0, 0);
            __builtin_amdgcn_s_setprio(0);
            cf = cn;
        }
    }

    // ---- epilogue: (acc + b2) * route_weight -> ybuf[slot][c] bf16
    // D layout: row(token) = quad*4 + r, col(outcol) = o*16 + l15
    const float* b2e = b2 + e * CCH;
    float wr_[4];
#pragma unroll
    for (int r = 0; r < 4; r++) {
        int row = quad * 4 + r;
        wr_[r] = (row < nrows) ? assign_w[abase + row] : 0.0f;
    }
#pragma unroll
    for (int o = 0; o < 16; o++) {
        float bias = b2e[o * 16 + l15];
#pragma unroll
        for (int r = 0; r < 4; r++) {
            int row = quad * 4 + r;
            if (row < nrows) {
                float v = (oacc[o][r] + bias) * wr_[r];
                ybuf[(size_t)(abase + row) * CCH + o * 16 + l15] = __float2bfloat16(v);
            }
        }
    }
}

// ---------------- K4: combine two expert outputs, transpose back, residual --
__global__ __launch_bounds__(256) void k_combine(
    const float* __restrict__ x, const __hip_bfloat16* __restrict__ ybuf,
    const int2* __restrict__ tok_slots, const float* __restrict__ scale,
    float* __restrict__ out)
{
    __shared__ __align__(16) unsigned short moe[CCH][36];   // 18 KB
    __shared__ int2 slots[32];
    int tid = threadIdx.x;
    int n0 = blockIdx.x * 32;
    if (tid < 32) slots[tid] = tok_slots[n0 + tid];
    __syncthreads();
    {
        int r = tid & 31, g0 = tid >> 5;
#pragma unroll
        for (int it = 0; it < 2; it++) {
            int g = g0 + 8 * it;
            int2 s = slots[r];
            const u16x8* px = (const u16x8*)(ybuf + (size_t)s.x * CCH + 16 * g);
            const u16x8* py = (const u16x8*)(ybuf + (size_t)s.y * CCH + 16 * g);
            u16x8 ax0 = px[0], ax1 = px[1], ay0 = py[0], ay1 = py[1];
#pragma unroll
            for (int k = 0; k < 8; k++) {
                moe[16 * g + k][r]     = f2bf_ubits(bfbits2f(ax0[k]) + bfbits2f(ay0[k]));
                moe[16 * g + 8 + k][r] = f2bf_ubits(bfbits2f(ax1[k]) + bfbits2f(ay1[k]));
            }
        }
    }
    __syncthreads();
    float sc = scale[0];
    int b = n0 >> 12, p0 = n0 & 4095;
    const float* xb = x + (size_t)b * CCH * HW + p0;
    float* ob = out + (size_t)b * CCH * HW + p0;
    int j = tid & 7, cbase = tid >> 3;
#pragma unroll
    for (int i = 0; i < 8; i++) {
        int c = cbase + 32 * i;
        float4 xv = *(const float4*)(xb + (size_t)c * HW + 4 * j);
        u16x4 mv = *(const u16x4*)&moe[c][4 * j];
        float4 o;
        o.x = xv.x + sc * bfbits2f(mv[0]);
        o.y = xv.y + sc * bfbits2f(mv[1]);
        o.z = xv.z + sc * bfbits2f(mv[2]);
        o.w = xv.w + sc * bfbits2f(mv[3]);
        *(float4*)(ob + (size_t)c * HW + 4 * j) = o;
    }
}

// ---------------- launch ----------------------------------------------------
extern "C" void kernel_launch(void* const* d_in, const int* in_sizes, int n_in,
                              void* d_out, int out_size, void* d_ws, size_t ws_size,
                              hipStream_t stream)
{
    const float* x     = (const float*)d_in[0];
    const float* Wr    = (const float*)d_in[1];
    const float* br    = (const float*)d_in[2];
    const float* W1    = (const float*)d_in[3];
    const float* b1    = (const float*)d_in[4];
    const float* W2    = (const float*)d_in[5];
    const float* b2    = (const float*)d_in[6];
    const float* scale = (const float*)d_in[7];
    float* out = (float*)d_out;

    char* ws = (char*)d_ws;
    __hip_bfloat16* tokens = (__hip_bfloat16*)(ws);                 // 33,554,432 B
    __hip_bfloat16* w1t    = (__hip_bfloat16*)(ws + 33554432);      //  2,097,152 B
    __hip_bfloat16* w2t    = (__hip_bfloat16*)(ws + 35651584);      //  2,097,152 B
    __hip_bfloat16* ybuf   = (__hip_bfloat16*)(ws + 37748736);      // 67,108,864 B
    int*    assign_tok = (int*)   (ws + 104857600);                 //    524,288 B
    float*  assign_w   = (float*) (ws + 105381888);                 //    524,288 B
    int2*   tok_slots  = (int2*)  (ws + 105906176);                 //    524,288 B
    int*    pair       = (int*)   (ws + 106430464);                 //    262,144 B
    float2* wts        = (float2*)(ws + 106692608);                 //    524,288 B
    int*    meta       = (int*)   (ws + 107216896);                 //        256 B

    k_transpose_both<<<512, 256, 0, stream>>>(W1, W2, w1t, w2t, meta);
    k_router<<<2048, 256, 0, stream>>>(x, Wr, br, tokens, pair, wts, meta);
    k_scatter<<<256, 256, 0, stream>>>(pair, wts, meta, assign_tok, assign_w, tok_slots);
    k_expert<<<8200, 64, 0, stream>>>(tokens, w1t, w2t, b1, b2, meta,
                                      assign_tok, assign_w, ybuf);
    k_combine<<<2048, 256, 0, stream>>>(x, ybuf, tok_slots, scale, out);
}

// Round 9
// 368.713 us; speedup vs baseline: 2.1517x; 2.1517x over previous
//
#include <hip/hip_runtime.h>
#include <hip/hip_bf16.h>
#include <math.h>

#define HW   4096
#define CCH  256
#define NE   8
#define HID  512
#define NTOK 65536
#define PADH 260   // Hs row pitch (elems): +4 pad -> conflict-free writes, 4-way reads

typedef short s16x8 __attribute__((ext_vector_type(8)));
typedef float f32x4 __attribute__((ext_vector_type(4)));
typedef unsigned short u16x8 __attribute__((ext_vector_type(8)));
typedef unsigned short u16x4 __attribute__((ext_vector_type(4)));
typedef unsigned int u32x4 __attribute__((ext_vector_type(4)));   // clang ext-vector: legal for nontemporal builtins

// Fast exact-enough GELU: v * sigmoid(2u), u = 0.79788456*(v + 0.044715 v^3).
__device__ __forceinline__ float fast_gelu(float v) {
    float v2 = v * v;
    float s  = v * fmaf(0.10294324f, v2, 2.3022079f);
    float e  = exp2f(-s);
    return v * __builtin_amdgcn_rcpf(1.0f + e);
}

__device__ __forceinline__ float bfbits2f(unsigned short h) {
    return __uint_as_float(((unsigned)h) << 16);
}

__device__ __forceinline__ short f2bf_bits(float f) {
    __hip_bfloat16 b = __float2bfloat16(f);
    return *reinterpret_cast<short*>(&b);
}

__device__ __forceinline__ unsigned short f2bf_ubits(float f) {
    __hip_bfloat16 b = __float2bfloat16(f);
    return *reinterpret_cast<unsigned short*>(&b);
}

// ---------------- K transpose+cast for BOTH weights (+ meta zero) -----------
// blocks [0,256): W1 (E,256,512)->(E,512,256); blocks [256,512): W2 -> (E,256,512)
__global__ __launch_bounds__(256) void k_transpose_both(
    const float* __restrict__ W1, const float* __restrict__ W2,
    __hip_bfloat16* __restrict__ w1t, __hip_bfloat16* __restrict__ w2t,
    int* __restrict__ meta)
{
    __shared__ float t[64][65];
    if (blockIdx.x == 0 && threadIdx.x < 16) meta[threadIdx.x] = 0;  // counts+cursors
    int bb = blockIdx.x;
    const float* in; __hip_bfloat16* out; int R, CC;
    if (bb < 256) { in = W1; out = w1t; R = 256; CC = 512; }
    else          { in = W2; out = w2t; R = 512; CC = 256; bb -= 256; }
    int tilesC = CC >> 6;
    int per = (R >> 6) * tilesC;
    int e = bb / per, tt = bb % per;
    int r0 = (tt / tilesC) << 6, c0 = (tt % tilesC) << 6;
    const float* ip = in + (size_t)e * R * CC;
    __hip_bfloat16* op = out + (size_t)e * R * CC;
    int lane = threadIdx.x & 63, g = threadIdx.x >> 6;
    for (int i = 0; i < 16; i++) {
        int r = i * 4 + g;
        t[r][lane] = ip[(size_t)(r0 + r) * CC + c0 + lane];
    }
    __syncthreads();
    for (int i = 0; i < 16; i++) {
        int r = i * 4 + g;
        op[(size_t)(c0 + r) * R + r0 + lane] = __float2bfloat16(t[lane][r]);
    }
}

// ---------------- K0: router, 32-token tiles, fused reg-logits --------------
__global__ __launch_bounds__(256) void k_router(
    const float* __restrict__ x, const float* __restrict__ Wr, const float* __restrict__ br,
    __hip_bfloat16* __restrict__ tokens, int* __restrict__ pair, float2* __restrict__ wts,
    int* __restrict__ meta /* counts at [0..8) */)
{
    __shared__ float xt[CCH][33];      // 33.8 KB
    __shared__ float wrp[2304];        // Wr staged [c*8+e]; reused as plg
    __shared__ float lg[32][NE];
    __shared__ int lc[NE];
    int tid = threadIdx.x;
    int n0 = blockIdx.x * 32;
    int b = n0 >> 12, p0 = n0 & 4095;
    const float* xb = x + (size_t)b * CCH * HW + p0;
    for (int i = tid; i < CCH * NE; i += 256) wrp[i] = Wr[i];
    if (tid < NE) lc[tid] = 0;
    __syncthreads();
    int j = tid & 31, cg = tid >> 5;
    float pacc[8];
#pragma unroll
    for (int e = 0; e < 8; e++) pacc[e] = 0.f;
    for (int i = 0; i < 32; i++) {
        int c = cg + 8 * i;
        float xv = xb[(size_t)c * HW + j];
        xt[c][j] = xv;
        const float4* wp = (const float4*)(wrp + c * 8);
        float4 wa = wp[0], wb2 = wp[1];
        pacc[0] = fmaf(xv, wa.x, pacc[0]);
        pacc[1] = fmaf(xv, wa.y, pacc[1]);
        pacc[2] = fmaf(xv, wa.z, pacc[2]);
        pacc[3] = fmaf(xv, wa.w, pacc[3]);
        pacc[4] = fmaf(xv, wb2.x, pacc[4]);
        pacc[5] = fmaf(xv, wb2.y, pacc[5]);
        pacc[6] = fmaf(xv, wb2.z, pacc[6]);
        pacc[7] = fmaf(xv, wb2.w, pacc[7]);
    }
    __syncthreads();
    float* plg = wrp;
#pragma unroll
    for (int e = 0; e < 8; e++) plg[(cg * 32 + j) * 9 + e] = pacc[e];
    __syncthreads();
    {
        int jj = tid & 31, e = tid >> 5;
        float s = br[e];
#pragma unroll
        for (int g = 0; g < 8; g++) s += plg[(g * 32 + jj) * 9 + e];
        lg[jj][e] = s;
    }
    __syncthreads();
    if (tid < 32) {
        float v0 = -1e30f, v1 = -1e30f; int i0 = 0, i1 = 0;
        for (int e = 0; e < NE; e++) {
            float l = lg[tid][e];
            if (l > v0)      { v1 = v0; i1 = i0; v0 = l; i0 = e; }
            else if (l > v1) { v1 = l; i1 = e; }
        }
        float e1 = expf(v1 - v0);
        float s = 1.0f + e1;
        wts[n0 + tid] = make_float2(1.0f / s, e1 / s);
        pair[n0 + tid] = i0 | (i1 << 8);
        atomicAdd(&lc[i0], 1);
        atomicAdd(&lc[i1], 1);
    }
    __syncthreads();
    if (tid < NE && lc[tid] > 0) atomicAdd(&meta[tid], lc[tid]);
#pragma unroll
    for (int i = 0; i < 4; i++) {
        int c0 = (cg + 8 * i) * 8;
        s16x8 v;
#pragma unroll
        for (int k = 0; k < 8; k++) v[k] = f2bf_bits(xt[c0 + k][j]);
        *(s16x8*)(tokens + (size_t)(n0 + j) * CCH + c0) = v;
    }
}

// ---------------- K2: scatter tokens into per-expert lists (scan fused) -----
// meta: [0..8) counts, [8..16) cursors, [16..25) offsets, [25..34) tilestart, [34] total
// 64-token tiles (matches k_expert r0 = tile<<6).
__global__ __launch_bounds__(256) void k_scatter(
    const int* __restrict__ pair, const float2* __restrict__ wts,
    int* __restrict__ meta, int* __restrict__ assign_tok, float* __restrict__ assign_w,
    int2* __restrict__ tok_slots)
{
    __shared__ int lcount[NE];
    __shared__ int lbase[NE];
    __shared__ int soff[NE];
    int tid = threadIdx.x;
    int n = blockIdx.x * 256 + tid;
    if (tid < NE) lcount[tid] = 0;
    __syncthreads();
    int pr = pair[n];
    int e0 = pr & 0xff, e1 = (pr >> 8) & 0xff;
    int p0 = atomicAdd(&lcount[e0], 1);
    int p1 = atomicAdd(&lcount[e1], 1);
    __syncthreads();
    if (tid == 0) {
        int off = 0, toff = 0;
        for (int ee = 0; ee < NE; ee++) {
            soff[ee] = off;
            int c = meta[ee];
            if (blockIdx.x == 0) { meta[16 + ee] = off; meta[25 + ee] = toff; }
            off += c;
            toff += (c + 63) >> 6;
        }
        if (blockIdx.x == 0) { meta[24] = off; meta[33] = toff; meta[34] = toff; }
    }
    if (tid < NE) lbase[tid] = atomicAdd(&meta[8 + tid], lcount[tid]);
    __syncthreads();
    float2 w = wts[n];
    int s0 = soff[e0] + lbase[e0] + p0;
    int s1 = soff[e1] + lbase[e1] + p1;
    assign_tok[s0] = n; assign_w[s0] = w.x;
    assign_tok[s1] = n; assign_w[s1] = w.y;
    tok_slots[n] = make_int2(s0, s1);
}

// ---------------- K3: grouped fused MLP (the hot kernel) --------------------
// R4-proven structure (XCD swizzle, 4 barriers, cross-barrier prefetch, fast
// GELU). R8: token staging loads + ybuf stores are NON-TEMPORAL -> the two
// 8.4MB/XCD/round streams stop washing the 4MB L2, so the ~1MB/XCD weight
// working set stays L2-resident (weight stream was the measured 6.5 TB/s
// bottleneck: R4 1.05GB/173us, R2 2.1GB/304us, R7 4.2GB/640us).
__global__ __launch_bounds__(512, 4) void k_expert(
    const __hip_bfloat16* __restrict__ tokens,
    const __hip_bfloat16* __restrict__ w1t,   // (E, HID, C)  = W1^T per expert
    const __hip_bfloat16* __restrict__ w2t,   // (E, C, HID)  = W2^T per expert
    const float* __restrict__ b1, const float* __restrict__ b2,
    const int* __restrict__ meta,
    const int* __restrict__ assign_tok, const float* __restrict__ assign_w,
    __hip_bfloat16* __restrict__ ybuf)
{
    __shared__ __align__(16) __hip_bfloat16 Af[64 * 256];      // 32 KB
    __shared__ __align__(16) __hip_bfloat16 Hs[64 * PADH];     // 33.3 KB
    __shared__ float wrow[64];
    __shared__ int trow[64];

    int total = meta[34];
    int swz = (int)blockIdx.x;
    int bid = (swz & 7) * 257 + (swz >> 3);    // grid 2056 = 8*257, bijective
    if (bid >= total) return;
    int e = 0;
    while (e < 7 && bid >= meta[25 + e + 1]) e++;
    int tile = bid - meta[25 + e];
    int cnt = meta[e];
    int r0 = tile << 6;
    int abase = meta[16 + e] + r0;
    int nrows = cnt - r0; if (nrows > 64) nrows = 64;

    int tid = threadIdx.x;
    if (tid < 64) {
        if (tid < nrows) { trow[tid] = assign_tok[abase + tid]; wrow[tid] = assign_w[abase + tid]; }
        else             { trow[tid] = 0; wrow[tid] = 0.0f; }
    }
    __syncthreads();

    // ---- stage A tile into LDS (frag-linear; NON-TEMPORAL 16B global reads)
    {
        u32x4* dst = (u32x4*)Af;
#pragma unroll
        for (int j = 0; j < 4; j++) {
            int row = j * 16 + (tid & 15);
            int chunk = (tid >> 4) & 31;
            dst[j * 512 + tid] = __builtin_nontemporal_load(
                ((const u32x4*)(tokens + (size_t)trow[row] * CCH)) + chunk);
        }
    }

    int lane = tid & 63, wv = tid >> 6;      // wv in [0,8)
    int quad = lane >> 4, l15 = lane & 15;

    const __hip_bfloat16* w1e = w1t + (size_t)e * HID * CCH;
    const __hip_bfloat16* w2e = w2t + (size_t)e * CCH * HID;
    const float* b1e = b1 + e * HID;
    const float* b2e = b2 + e * CCH;

    const s16x8* apb = (const s16x8*)Af + quad * 16 + l15;   // + mt*512 + kk*64

    auto G1Q = [&](int h, int off) {
        return (const s16x8*)(w1e + (size_t)(h * 256 + wv * 32 + off + l15) * CCH) + quad;
    };
    auto G2Q = [&](int h, int off) {
        return (const s16x8*)(w2e + (size_t)(wv * 32 + off + l15) * HID + h * 256) + quad;
    };

    f32x4 oacc[4][2];
#pragma unroll
    for (int i = 0; i < 4; i++)
#pragma unroll
        for (int j = 0; j < 2; j++) oacc[i][j] = (f32x4){0.f, 0.f, 0.f, 0.f};

    // issue h=0 GEMM1 first B-frags and epilogue biases before the A barrier
    s16x8 bf0 = G1Q(0, 0)[0], bf1 = G1Q(0, 16)[0];
    float ob0 = b2e[wv * 32 + l15];
    float ob1 = b2e[wv * 32 + 16 + l15];

    __syncthreads();   // A tile visible (barrier drain also completes bf0/bf1)

#pragma unroll
    for (int h = 0; h < 2; h++) {
        const s16x8* bq0 = G1Q(h, 0);
        const s16x8* bq1 = G1Q(h, 16);

        f32x4 hacc[4][2];
#pragma unroll
        for (int i = 0; i < 4; i++)
#pragma unroll
            for (int j = 0; j < 2; j++) hacc[i][j] = (f32x4){0.f, 0.f, 0.f, 0.f};

        // ---- GEMM1: hacc[mt][nt] over K=256
#pragma unroll
        for (int kk = 0; kk < 8; kk++) {
            s16x8 bn0, bn1;
            if (kk < 7) { bn0 = bq0[(kk + 1) * 4]; bn1 = bq1[(kk + 1) * 4]; }
            s16x8 af[4];
#pragma unroll
            for (int mt = 0; mt < 4; mt++) af[mt] = apb[mt * 512 + kk * 4 * 16];
            __builtin_amdgcn_s_setprio(1);
#pragma unroll
            for (int mt = 0; mt < 4; mt++) {
                hacc[mt][0] = __builtin_amdgcn_mfma_f32_16x16x32_bf16(af[mt], bf0, hacc[mt][0], 0, 0, 0);
                hacc[mt][1] = __builtin_amdgcn_mfma_f32_16x16x32_bf16(af[mt], bf1, hacc[mt][1], 0, 0, 0);
            }
            __builtin_amdgcn_s_setprio(0);
            bf0 = bn0; bf1 = bn1;
        }

        // issue next-phase operands early (completed under GELU / barrier drain)
        const s16x8* b2q0 = G2Q(h, 0);
        const s16x8* b2q1 = G2Q(h, 16);
        s16x8 cf0 = b2q0[0], cf1 = b2q1[0];
        float biasA = b1e[h * 256 + wv * 32 + l15];
        float biasB = b1e[h * 256 + wv * 32 + 16 + l15];
        if (h == 0) { bf0 = G1Q(1, 0)[0]; bf1 = G1Q(1, 16)[0]; }

        // Barrier needed only at h=1 (Hs reuse); h=0's Hs untouched since start.
        if (h == 1) __syncthreads();

        // ---- bias + fast GELU -> Hs (local col cl in [0,256))
#pragma unroll
        for (int nt = 0; nt < 2; nt++) {
            int cl = wv * 32 + nt * 16 + l15;
            float bias = nt ? biasB : biasA;
#pragma unroll
            for (int mt = 0; mt < 4; mt++)
#pragma unroll
                for (int r = 0; r < 4; r++) {
                    int row = mt * 16 + quad * 4 + r;
                    float v = hacc[mt][nt][r] + bias;
                    Hs[row * PADH + cl] = __float2bfloat16(fast_gelu(v));
                }
        }
        __syncthreads();   // Hs complete before GEMM2 reads

        // ---- GEMM2: A = Hs rows (LDS), B = W2^T rows (global/L2), K=256
#pragma unroll
        for (int kk = 0; kk < 8; kk++) {
            s16x8 cn0, cn1;
            if (kk < 7) { cn0 = b2q0[(kk + 1) * 4]; cn1 = b2q1[(kk + 1) * 4]; }
            s16x8 hf[4];
#pragma unroll
            for (int mt = 0; mt < 4; mt++)
                hf[mt] = *(const s16x8*)(Hs + (mt * 16 + l15) * PADH + kk * 32 + quad * 8);
            __builtin_amdgcn_s_setprio(1);
#pragma unroll
            for (int mt = 0; mt < 4; mt++) {
                oacc[mt][0] = __builtin_amdgcn_mfma_f32_16x16x32_bf16(hf[mt], cf0, oacc[mt][0], 0, 0, 0);
                oacc[mt][1] = __builtin_amdgcn_mfma_f32_16x16x32_bf16(hf[mt], cf1, oacc[mt][1], 0, 0, 0);
            }
            __builtin_amdgcn_s_setprio(0);
            cf0 = cn0; cf1 = cn1;
        }
        // no barrier at h=0 end: the h=1 pre-GELU barrier protects Hs
    }

    // ---- epilogue: (acc + b2) * route_weight -> ybuf (NON-TEMPORAL stores)
#pragma unroll
    for (int nt = 0; nt < 2; nt++) {
        int cc = wv * 32 + nt * 16 + l15;
        float bias = nt ? ob1 : ob0;
#pragma unroll
        for (int mt = 0; mt < 4; mt++) {
#pragma unroll
            for (int r = 0; r < 4; r++) {
                int row = mt * 16 + quad * 4 + r;
                if (row < nrows) {
                    float v = (oacc[mt][nt][r] + bias) * wrow[row];
                    __builtin_nontemporal_store(f2bf_bits(v),
                        (short*)(ybuf + (size_t)(abase + row) * CCH + cc));
                }
            }
        }
    }
}

// ---------------- K4: combine two expert outputs, transpose back, residual --
__global__ __launch_bounds__(256) void k_combine(
    const float* __restrict__ x, const __hip_bfloat16* __restrict__ ybuf,
    const int2* __restrict__ tok_slots, const float* __restrict__ scale,
    float* __restrict__ out)
{
    __shared__ __align__(16) unsigned short moe[CCH][36];   // 18 KB
    __shared__ int2 slots[32];
    int tid = threadIdx.x;
    int n0 = blockIdx.x * 32;
    if (tid < 32) slots[tid] = tok_slots[n0 + tid];
    __syncthreads();
    {
        int r = tid & 31, g0 = tid >> 5;
#pragma unroll
        for (int it = 0; it < 2; it++) {
            int g = g0 + 8 * it;
            int2 s = slots[r];
            const u16x8* px = (const u16x8*)(ybuf + (size_t)s.x * CCH + 16 * g);
            const u16x8* py = (const u16x8*)(ybuf + (size_t)s.y * CCH + 16 * g);
            u16x8 ax0 = px[0], ax1 = px[1], ay0 = py[0], ay1 = py[1];
#pragma unroll
            for (int k = 0; k < 8; k++) {
                moe[16 * g + k][r]     = f2bf_ubits(bfbits2f(ax0[k]) + bfbits2f(ay0[k]));
                moe[16 * g + 8 + k][r] = f2bf_ubits(bfbits2f(ax1[k]) + bfbits2f(ay1[k]));
            }
        }
    }
    __syncthreads();
    float sc = scale[0];
    int b = n0 >> 12, p0 = n0 & 4095;
    const float* xb = x + (size_t)b * CCH * HW + p0;
    float* ob = out + (size_t)b * CCH * HW + p0;
    int j = tid & 7, cbase = tid >> 3;
#pragma unroll
    for (int i = 0; i < 8; i++) {
        int c = cbase + 32 * i;
        float4 xv = *(const float4*)(xb + (size_t)c * HW + 4 * j);
        u16x4 mv = *(const u16x4*)&moe[c][4 * j];
        float4 o;
        o.x = xv.x + sc * bfbits2f(mv[0]);
        o.y = xv.y + sc * bfbits2f(mv[1]);
        o.z = xv.z + sc * bfbits2f(mv[2]);
        o.w = xv.w + sc * bfbits2f(mv[3]);
        *(float4*)(ob + (size_t)c * HW + 4 * j) = o;
    }
}

// ---------------- launch ----------------------------------------------------
extern "C" void kernel_launch(void* const* d_in, const int* in_sizes, int n_in,
                              void* d_out, int out_size, void* d_ws, size_t ws_size,
                              hipStream_t stream)
{
    const float* x     = (const float*)d_in[0];
    const float* Wr    = (const float*)d_in[1];
    const float* br    = (const float*)d_in[2];
    const float* W1    = (const float*)d_in[3];
    const float* b1    = (const float*)d_in[4];
    const float* W2    = (const float*)d_in[5];
    const float* b2    = (const float*)d_in[6];
    const float* scale = (const float*)d_in[7];
    float* out = (float*)d_out;

    char* ws = (char*)d_ws;
    __hip_bfloat16* tokens = (__hip_bfloat16*)(ws);                 // 33,554,432 B
    __hip_bfloat16* w1t    = (__hip_bfloat16*)(ws + 33554432);      //  2,097,152 B
    __hip_bfloat16* w2t    = (__hip_bfloat16*)(ws + 35651584);      //  2,097,152 B
    __hip_bfloat16* ybuf   = (__hip_bfloat16*)(ws + 37748736);      // 67,108,864 B
    int*    assign_tok = (int*)   (ws + 104857600);                 //    524,288 B
    float*  assign_w   = (float*) (ws + 105381888);                 //    524,288 B
    int2*   tok_slots  = (int2*)  (ws + 105906176);                 //    524,288 B
    int*    pair       = (int*)   (ws + 106430464);                 //    262,144 B
    float2* wts        = (float2*)(ws + 106692608);                 //    524,288 B
    int*    meta       = (int*)   (ws + 107216896);                 //        256 B

    k_transpose_both<<<512, 256, 0, stream>>>(W1, W2, w1t, w2t, meta);
    k_router<<<2048, 256, 0, stream>>>(x, Wr, br, tokens, pair, wts, meta);
    k_scatter<<<256, 256, 0, stream>>>(pair, wts, meta, assign_tok, assign_w, tok_slots);
    k_expert<<<2056, 512, 0, stream>>>(tokens, w1t, w2t, b1, b2, meta,
                                       assign_tok, assign_w, ybuf);
    k_combine<<<2048, 256, 0, stream>>>(x, ybuf, tok_slots, scale, out);
}

// Round 10
// 333.133 us; speedup vs baseline: 2.3816x; 1.1068x over previous
//
#include <hip/hip_runtime.h>
#include <hip/hip_bf16.h>
#include <math.h>

#define HW   4096
#define CCH  256
#define NE   8
#define HID  512
#define NTOK 65536
#define PADH 260   // Hs row pitch (elems): +4 pad -> conflict-free writes, 4-way reads

typedef short s16x8 __attribute__((ext_vector_type(8)));
typedef float f32x4 __attribute__((ext_vector_type(4)));
typedef unsigned short u16x8 __attribute__((ext_vector_type(8)));
typedef unsigned short u16x4 __attribute__((ext_vector_type(4)));

// Fast exact-enough GELU: v * sigmoid(2u), u = 0.79788456*(v + 0.044715 v^3).
__device__ __forceinline__ float fast_gelu(float v) {
    float v2 = v * v;
    float s  = v * fmaf(0.10294324f, v2, 2.3022079f);
    float e  = exp2f(-s);
    return v * __builtin_amdgcn_rcpf(1.0f + e);
}

__device__ __forceinline__ float bfbits2f(unsigned short h) {
    return __uint_as_float(((unsigned)h) << 16);
}

__device__ __forceinline__ short f2bf_bits(float f) {
    __hip_bfloat16 b = __float2bfloat16(f);
    return *reinterpret_cast<short*>(&b);
}

__device__ __forceinline__ unsigned short f2bf_ubits(float f) {
    __hip_bfloat16 b = __float2bfloat16(f);
    return *reinterpret_cast<unsigned short*>(&b);
}

// ---------------- K transpose+cast for BOTH weights (+ meta zero) -----------
__global__ __launch_bounds__(256) void k_transpose_both(
    const float* __restrict__ W1, const float* __restrict__ W2,
    __hip_bfloat16* __restrict__ w1t, __hip_bfloat16* __restrict__ w2t,
    int* __restrict__ meta)
{
    __shared__ float t[64][65];
    if (blockIdx.x == 0 && threadIdx.x < 16) meta[threadIdx.x] = 0;  // counts+cursors
    int bb = blockIdx.x;
    const float* in; __hip_bfloat16* out; int R, CC;
    if (bb < 256) { in = W1; out = w1t; R = 256; CC = 512; }
    else          { in = W2; out = w2t; R = 512; CC = 256; bb -= 256; }
    int tilesC = CC >> 6;
    int per = (R >> 6) * tilesC;
    int e = bb / per, tt = bb % per;
    int r0 = (tt / tilesC) << 6, c0 = (tt % tilesC) << 6;
    const float* ip = in + (size_t)e * R * CC;
    __hip_bfloat16* op = out + (size_t)e * R * CC;
    int lane = threadIdx.x & 63, g = threadIdx.x >> 6;
    for (int i = 0; i < 16; i++) {
        int r = i * 4 + g;
        t[r][lane] = ip[(size_t)(r0 + r) * CC + c0 + lane];
    }
    __syncthreads();
    for (int i = 0; i < 16; i++) {
        int r = i * 4 + g;
        op[(size_t)(c0 + r) * R + r0 + lane] = __float2bfloat16(t[lane][r]);
    }
}

// ---------------- K0: router, 32-token tiles, fused reg-logits --------------
__global__ __launch_bounds__(256) void k_router(
    const float* __restrict__ x, const float* __restrict__ Wr, const float* __restrict__ br,
    __hip_bfloat16* __restrict__ tokens, int* __restrict__ pair, float2* __restrict__ wts,
    int* __restrict__ meta /* counts at [0..8) */)
{
    __shared__ float xt[CCH][33];      // 33.8 KB
    __shared__ float wrp[2304];        // Wr staged [c*8+e]; reused as plg
    __shared__ float lg[32][NE];
    __shared__ int lc[NE];
    int tid = threadIdx.x;
    int n0 = blockIdx.x * 32;
    int b = n0 >> 12, p0 = n0 & 4095;
    const float* xb = x + (size_t)b * CCH * HW + p0;
    for (int i = tid; i < CCH * NE; i += 256) wrp[i] = Wr[i];
    if (tid < NE) lc[tid] = 0;
    __syncthreads();
    int j = tid & 31, cg = tid >> 5;
    float pacc[8];
#pragma unroll
    for (int e = 0; e < 8; e++) pacc[e] = 0.f;
    for (int i = 0; i < 32; i++) {
        int c = cg + 8 * i;
        float xv = xb[(size_t)c * HW + j];
        xt[c][j] = xv;
        const float4* wp = (const float4*)(wrp + c * 8);
        float4 wa = wp[0], wb2 = wp[1];
        pacc[0] = fmaf(xv, wa.x, pacc[0]);
        pacc[1] = fmaf(xv, wa.y, pacc[1]);
        pacc[2] = fmaf(xv, wa.z, pacc[2]);
        pacc[3] = fmaf(xv, wa.w, pacc[3]);
        pacc[4] = fmaf(xv, wb2.x, pacc[4]);
        pacc[5] = fmaf(xv, wb2.y, pacc[5]);
        pacc[6] = fmaf(xv, wb2.z, pacc[6]);
        pacc[7] = fmaf(xv, wb2.w, pacc[7]);
    }
    __syncthreads();
    float* plg = wrp;
#pragma unroll
    for (int e = 0; e < 8; e++) plg[(cg * 32 + j) * 9 + e] = pacc[e];
    __syncthreads();
    {
        int jj = tid & 31, e = tid >> 5;
        float s = br[e];
#pragma unroll
        for (int g = 0; g < 8; g++) s += plg[(g * 32 + jj) * 9 + e];
        lg[jj][e] = s;
    }
    __syncthreads();
    if (tid < 32) {
        float v0 = -1e30f, v1 = -1e30f; int i0 = 0, i1 = 0;
        for (int e = 0; e < NE; e++) {
            float l = lg[tid][e];
            if (l > v0)      { v1 = v0; i1 = i0; v0 = l; i0 = e; }
            else if (l > v1) { v1 = l; i1 = e; }
        }
        float e1 = expf(v1 - v0);
        float s = 1.0f + e1;
        wts[n0 + tid] = make_float2(1.0f / s, e1 / s);
        pair[n0 + tid] = i0 | (i1 << 8);
        atomicAdd(&lc[i0], 1);
        atomicAdd(&lc[i1], 1);
    }
    __syncthreads();
    if (tid < NE && lc[tid] > 0) atomicAdd(&meta[tid], lc[tid]);
#pragma unroll
    for (int i = 0; i < 4; i++) {
        int c0 = (cg + 8 * i) * 8;
        s16x8 v;
#pragma unroll
        for (int k = 0; k < 8; k++) v[k] = f2bf_bits(xt[c0 + k][j]);
        *(s16x8*)(tokens + (size_t)(n0 + j) * CCH + c0) = v;
    }
}

// ---------------- K2: scatter tokens into per-expert lists (scan fused) -----
// meta: [0..8) counts, [8..16) cursors, [16..25) offsets, [25..34) tilestart, [34] total
// 128-token tiles (k_expert r0 = tile<<7).
__global__ __launch_bounds__(256) void k_scatter(
    const int* __restrict__ pair, const float2* __restrict__ wts,
    int* __restrict__ meta, int* __restrict__ assign_tok, float* __restrict__ assign_w,
    int2* __restrict__ tok_slots)
{
    __shared__ int lcount[NE];
    __shared__ int lbase[NE];
    __shared__ int soff[NE];
    int tid = threadIdx.x;
    int n = blockIdx.x * 256 + tid;
    if (tid < NE) lcount[tid] = 0;
    __syncthreads();
    int pr = pair[n];
    int e0 = pr & 0xff, e1 = (pr >> 8) & 0xff;
    int p0 = atomicAdd(&lcount[e0], 1);
    int p1 = atomicAdd(&lcount[e1], 1);
    __syncthreads();
    if (tid == 0) {
        int off = 0, toff = 0;
        for (int ee = 0; ee < NE; ee++) {
            soff[ee] = off;
            int c = meta[ee];
            if (blockIdx.x == 0) { meta[16 + ee] = off; meta[25 + ee] = toff; }
            off += c;
            toff += (c + 127) >> 7;
        }
        if (blockIdx.x == 0) { meta[24] = off; meta[33] = toff; meta[34] = toff; }
    }
    if (tid < NE) lbase[tid] = atomicAdd(&meta[8 + tid], lcount[tid]);
    __syncthreads();
    float2 w = wts[n];
    int s0 = soff[e0] + lbase[e0] + p0;
    int s1 = soff[e1] + lbase[e1] + p1;
    assign_tok[s0] = n; assign_w[s0] = w.x;
    assign_tok[s1] = n; assign_w[s1] = w.y;
    tok_slots[n] = make_int2(s0, s1);
}

// ---------------- K3: grouped fused MLP, 128-token tile ---------------------
// R10: M=128 per block (was 64) -> each 512KB weight pass feeds 2x MFMA work,
// halving the weight stream (1.05GB -> 0.53GB). The stream is the measured
// bottleneck: R4 1.05GB/173us, R2 2.1GB/304us, R7 4.2GB/640us, all ~6.5 TB/s
// regardless of structure/occupancy. 8 waves, 1 block/CU (regs ~220, LDS
// 132KB); 16 MFMAs per B-load pair (~310cyc) > L2 latency -> prefetch covers.
__global__ __launch_bounds__(512, 2) void k_expert(
    const __hip_bfloat16* __restrict__ tokens,
    const __hip_bfloat16* __restrict__ w1t,   // (E, HID, C)  = W1^T per expert
    const __hip_bfloat16* __restrict__ w2t,   // (E, C, HID)  = W2^T per expert
    const float* __restrict__ b1, const float* __restrict__ b2,
    const int* __restrict__ meta,
    const int* __restrict__ assign_tok, const float* __restrict__ assign_w,
    __hip_bfloat16* __restrict__ ybuf)
{
    __shared__ __align__(16) __hip_bfloat16 Af[128 * 256];     // 64 KB
    __shared__ __align__(16) __hip_bfloat16 Hs[128 * PADH];    // 66.6 KB
    __shared__ float wrow[128];
    __shared__ int trow[128];

    int total = meta[34];
    int swz = (int)blockIdx.x;
    int bid = (swz & 7) * 129 + (swz >> 3);    // grid 1032 = 8*129, bijective
    if (bid >= total) return;
    int e = 0;
    while (e < 7 && bid >= meta[25 + e + 1]) e++;
    int tile = bid - meta[25 + e];
    int cnt = meta[e];
    int r0 = tile << 7;
    int abase = meta[16 + e] + r0;
    int nrows = cnt - r0; if (nrows > 128) nrows = 128;

    int tid = threadIdx.x;
    if (tid < 128) {
        if (tid < nrows) { trow[tid] = assign_tok[abase + tid]; wrow[tid] = assign_w[abase + tid]; }
        else             { trow[tid] = 0; wrow[tid] = 0.0f; }
    }
    __syncthreads();

    // ---- stage A tile into LDS (frag-linear; lane-linear 16B writes)
    // unit U = mt*512 + (kk*4+quad)*16 + l15 : token row (U>>9)*16+(U&15),
    // k-chunk (U>>4)&31.  8 iters x 512 thr x 16B = 64KB.
    {
        uint2* dstchk; (void)dstchk;
        u16x8* dst = (u16x8*)Af;
#pragma unroll
        for (int j = 0; j < 8; j++) {
            int row = j * 16 + (tid & 15);
            int chunk = (tid >> 4) & 31;
            dst[j * 512 + tid] = ((const u16x8*)(tokens + (size_t)trow[row] * CCH))[chunk];
        }
    }

    int lane = tid & 63, wv = tid >> 6;      // wv in [0,8)
    int quad = lane >> 4, l15 = lane & 15;

    const __hip_bfloat16* w1e = w1t + (size_t)e * HID * CCH;
    const __hip_bfloat16* w2e = w2t + (size_t)e * CCH * HID;
    const float* b1e = b1 + e * HID;
    const float* b2e = b2 + e * CCH;

    const s16x8* apb = (const s16x8*)Af + quad * 16 + l15;   // + mt*512 + kk*64

    auto G1Q = [&](int h, int off) {
        return (const s16x8*)(w1e + (size_t)(h * 256 + wv * 32 + off + l15) * CCH) + quad;
    };
    auto G2Q = [&](int h, int off) {
        return (const s16x8*)(w2e + (size_t)(wv * 32 + off + l15) * HID + h * 256) + quad;
    };

    f32x4 oacc[8][2];
#pragma unroll
    for (int i = 0; i < 8; i++)
#pragma unroll
        for (int j = 0; j < 2; j++) oacc[i][j] = (f32x4){0.f, 0.f, 0.f, 0.f};

    // issue h=0 GEMM1 first B-frags and epilogue biases before the A barrier
    s16x8 bf0 = G1Q(0, 0)[0], bf1 = G1Q(0, 16)[0];
    float ob0 = b2e[wv * 32 + l15];
    float ob1 = b2e[wv * 32 + 16 + l15];

    __syncthreads();   // A tile visible (barrier drain also completes bf0/bf1)

#pragma unroll
    for (int h = 0; h < 2; h++) {
        const s16x8* bq0 = G1Q(h, 0);
        const s16x8* bq1 = G1Q(h, 16);

        f32x4 hacc[8][2];
#pragma unroll
        for (int i = 0; i < 8; i++)
#pragma unroll
            for (int j = 0; j < 2; j++) hacc[i][j] = (f32x4){0.f, 0.f, 0.f, 0.f};

        // ---- GEMM1: hacc[mt][nt] over K=256, M=128 (2 mt-groups of 4)
#pragma unroll
        for (int kk = 0; kk < 8; kk++) {
            s16x8 bn0, bn1;
            if (kk < 7) { bn0 = bq0[(kk + 1) * 4]; bn1 = bq1[(kk + 1) * 4]; }
#pragma unroll
            for (int g = 0; g < 2; g++) {
                s16x8 af[4];
#pragma unroll
                for (int m = 0; m < 4; m++) af[m] = apb[(g * 4 + m) * 512 + kk * 64];
                __builtin_amdgcn_s_setprio(1);
#pragma unroll
                for (int m = 0; m < 4; m++) {
                    hacc[g * 4 + m][0] = __builtin_amdgcn_mfma_f32_16x16x32_bf16(af[m], bf0, hacc[g * 4 + m][0], 0, 0, 0);
                    hacc[g * 4 + m][1] = __builtin_amdgcn_mfma_f32_16x16x32_bf16(af[m], bf1, hacc[g * 4 + m][1], 0, 0, 0);
                }
                __builtin_amdgcn_s_setprio(0);
            }
            bf0 = bn0; bf1 = bn1;
        }

        // issue next-phase operands early (completed under GELU / barrier drain)
        const s16x8* b2q0 = G2Q(h, 0);
        const s16x8* b2q1 = G2Q(h, 16);
        s16x8 cf0 = b2q0[0], cf1 = b2q1[0];
        float biasA = b1e[h * 256 + wv * 32 + l15];
        float biasB = b1e[h * 256 + wv * 32 + 16 + l15];
        if (h == 0) { bf0 = G1Q(1, 0)[0]; bf1 = G1Q(1, 16)[0]; }

        // Barrier needed only at h=1 (Hs reuse); h=0's Hs untouched since start.
        if (h == 1) __syncthreads();

        // ---- bias + fast GELU -> Hs (local col cl in [0,256), rows 0..127)
#pragma unroll
        for (int nt = 0; nt < 2; nt++) {
            int cl = wv * 32 + nt * 16 + l15;
            float bias = nt ? biasB : biasA;
#pragma unroll
            for (int mt = 0; mt < 8; mt++)
#pragma unroll
                for (int r = 0; r < 4; r++) {
                    int row = mt * 16 + quad * 4 + r;
                    float v = hacc[mt][nt][r] + bias;
                    Hs[row * PADH + cl] = __float2bfloat16(fast_gelu(v));
                }
        }
        __syncthreads();   // Hs complete before GEMM2 reads

        // ---- GEMM2: A = Hs rows (LDS), B = W2^T rows (global/L2), K=256
#pragma unroll
        for (int kk = 0; kk < 8; kk++) {
            s16x8 cn0, cn1;
            if (kk < 7) { cn0 = b2q0[(kk + 1) * 4]; cn1 = b2q1[(kk + 1) * 4]; }
#pragma unroll
            for (int g = 0; g < 2; g++) {
                s16x8 hf[4];
#pragma unroll
                for (int m = 0; m < 4; m++)
                    hf[m] = *(const s16x8*)(Hs + ((g * 4 + m) * 16 + l15) * PADH + kk * 32 + quad * 8);
                __builtin_amdgcn_s_setprio(1);
#pragma unroll
                for (int m = 0; m < 4; m++) {
                    oacc[g * 4 + m][0] = __builtin_amdgcn_mfma_f32_16x16x32_bf16(hf[m], cf0, oacc[g * 4 + m][0], 0, 0, 0);
                    oacc[g * 4 + m][1] = __builtin_amdgcn_mfma_f32_16x16x32_bf16(hf[m], cf1, oacc[g * 4 + m][1], 0, 0, 0);
                }
                __builtin_amdgcn_s_setprio(0);
            }
            cf0 = cn0; cf1 = cn1;
        }
        // no barrier at h=0 end: the h=1 pre-GELU barrier protects Hs
    }

    // ---- epilogue: (acc + b2) * route_weight -> ybuf[slot][c] bf16
#pragma unroll
    for (int nt = 0; nt < 2; nt++) {
        int cc = wv * 32 + nt * 16 + l15;
        float bias = nt ? ob1 : ob0;
#pragma unroll
        for (int mt = 0; mt < 8; mt++) {
#pragma unroll
            for (int r = 0; r < 4; r++) {
                int row = mt * 16 + quad * 4 + r;
                if (row < nrows) {
                    float v = (oacc[mt][nt][r] + bias) * wrow[row];
                    ybuf[(size_t)(abase + row) * CCH + cc] = __float2bfloat16(v);
                }
            }
        }
    }
}

// ---------------- K4: combine two expert outputs, transpose back, residual --
__global__ __launch_bounds__(256) void k_combine(
    const float* __restrict__ x, const __hip_bfloat16* __restrict__ ybuf,
    const int2* __restrict__ tok_slots, const float* __restrict__ scale,
    float* __restrict__ out)
{
    __shared__ __align__(16) unsigned short moe[CCH][36];   // 18 KB
    __shared__ int2 slots[32];
    int tid = threadIdx.x;
    int n0 = blockIdx.x * 32;
    if (tid < 32) slots[tid] = tok_slots[n0 + tid];
    __syncthreads();
    {
        int r = tid & 31, g0 = tid >> 5;
#pragma unroll
        for (int it = 0; it < 2; it++) {
            int g = g0 + 8 * it;
            int2 s = slots[r];
            const u16x8* px = (const u16x8*)(ybuf + (size_t)s.x * CCH + 16 * g);
            const u16x8* py = (const u16x8*)(ybuf + (size_t)s.y * CCH + 16 * g);
            u16x8 ax0 = px[0], ax1 = px[1], ay0 = py[0], ay1 = py[1];
#pragma unroll
            for (int k = 0; k < 8; k++) {
                moe[16 * g + k][r]     = f2bf_ubits(bfbits2f(ax0[k]) + bfbits2f(ay0[k]));
                moe[16 * g + 8 + k][r] = f2bf_ubits(bfbits2f(ax1[k]) + bfbits2f(ay1[k]));
            }
        }
    }
    __syncthreads();
    float sc = scale[0];
    int b = n0 >> 12, p0 = n0 & 4095;
    const float* xb = x + (size_t)b * CCH * HW + p0;
    float* ob = out + (size_t)b * CCH * HW + p0;
    int j = tid & 7, cbase = tid >> 3;
#pragma unroll
    for (int i = 0; i < 8; i++) {
        int c = cbase + 32 * i;
        float4 xv = *(const float4*)(xb + (size_t)c * HW + 4 * j);
        u16x4 mv = *(const u16x4*)&moe[c][4 * j];
        float4 o;
        o.x = xv.x + sc * bfbits2f(mv[0]);
        o.y = xv.y + sc * bfbits2f(mv[1]);
        o.z = xv.z + sc * bfbits2f(mv[2]);
        o.w = xv.w + sc * bfbits2f(mv[3]);
        *(float4*)(ob + (size_t)c * HW + 4 * j) = o;
    }
}

// ---------------- launch ----------------------------------------------------
extern "C" void kernel_launch(void* const* d_in, const int* in_sizes, int n_in,
                              void* d_out, int out_size, void* d_ws, size_t ws_size,
                              hipStream_t stream)
{
    const float* x     = (const float*)d_in[0];
    const float* Wr    = (const float*)d_in[1];
    const float* br    = (const float*)d_in[2];
    const float* W1    = (const float*)d_in[3];
    const float* b1    = (const float*)d_in[4];
    const float* W2    = (const float*)d_in[5];
    const float* b2    = (const float*)d_in[6];
    const float* scale = (const float*)d_in[7];
    float* out = (float*)d_out;

    char* ws = (char*)d_ws;
    __hip_bfloat16* tokens = (__hip_bfloat16*)(ws);                 // 33,554,432 B
    __hip_bfloat16* w1t    = (__hip_bfloat16*)(ws + 33554432);      //  2,097,152 B
    __hip_bfloat16* w2t    = (__hip_bfloat16*)(ws + 35651584);      //  2,097,152 B
    __hip_bfloat16* ybuf   = (__hip_bfloat16*)(ws + 37748736);      // 67,108,864 B
    int*    assign_tok = (int*)   (ws + 104857600);                 //    524,288 B
    float*  assign_w   = (float*) (ws + 105381888);                 //    524,288 B
    int2*   tok_slots  = (int2*)  (ws + 105906176);                 //    524,288 B
    int*    pair       = (int*)   (ws + 106430464);                 //    262,144 B
    float2* wts        = (float2*)(ws + 106692608);                 //    524,288 B
    int*    meta       = (int*)   (ws + 107216896);                 //        256 B

    k_transpose_both<<<512, 256, 0, stream>>>(W1, W2, w1t, w2t, meta);
    k_router<<<2048, 256, 0, stream>>>(x, Wr, br, tokens, pair, wts, meta);
    k_scatter<<<256, 256, 0, stream>>>(pair, wts, meta, assign_tok, assign_w, tok_slots);
    k_expert<<<1032, 512, 0, stream>>>(tokens, w1t, w2t, b1, b2, meta,
                                       assign_tok, assign_w, ybuf);
    k_combine<<<2048, 256, 0, stream>>>(x, ybuf, tok_slots, scale, out);
}